// Round 2
// baseline (228.763 us; speedup 1.0000x reference)
//
#include <hip/hip_runtime.h>

#define NB   131072   // batch rows
#define TPB  128      // threads per block = rows per block (4 blocks/CU)
#define FANIN 260

__device__ __forceinline__ float sigm_(float x) { return 1.0f / (1.0f + __expf(-x)); }
__device__ __forceinline__ float tanh_(float x) { return 1.0f - 2.0f / (__expf(2.0f * x) + 1.0f); }

// Repack the four [4,260] weight matrices into k-major Wp[k][16] (gw = g*4+w)
// and fuse bias+theta into bth[16]. Runs every launch (ws is re-poisoned).
__global__ void qlstm_prep(const float* __restrict__ Wf, const float* __restrict__ bf,
                           const float* __restrict__ Wi, const float* __restrict__ bi,
                           const float* __restrict__ Wu, const float* __restrict__ bu,
                           const float* __restrict__ Wo, const float* __restrict__ bo,
                           const float* __restrict__ thf, const float* __restrict__ thi,
                           const float* __restrict__ thu, const float* __restrict__ tho,
                           float* __restrict__ Wp, float* __restrict__ bth) {
    int t = blockIdx.x * blockDim.x + threadIdx.x;
    if (t < FANIN * 16) {
        int k = t >> 4, gw = t & 15, g = gw >> 2, w = gw & 3;
        const float* Wg = (g == 0) ? Wf : (g == 1) ? Wi : (g == 2) ? Wu : Wo;
        Wp[t] = Wg[w * FANIN + k];
    }
    if (t < 16) {
        int g = t >> 2, w = t & 3;
        const float* bg = (g == 0) ? bf  : (g == 1) ? bi  : (g == 2) ? bu  : bo;
        const float* tg = (g == 0) ? thf : (g == 1) ? thi : (g == 2) ? thu : tho;
        bth[t] = bg[w] + tg[w];
    }
}

__global__ __launch_bounds__(TPB) void qlstm_main(
        const float* __restrict__ x, const float* __restrict__ hx,
        const float* __restrict__ cx, const float* __restrict__ Wp,
        const float* __restrict__ bth, float* __restrict__ out) {
    // LDS tile: 128 rows x 32 cols, stride 33 -> read bank (tid+kk)%32,
    // conflict-free (2-way aliasing across half-waves is free).
    __shared__ float xs[TPB * 33];

    const int tid  = threadIdx.x;
    const int row0 = blockIdx.x * TPB;
    const int row  = row0 + tid;

    // Issue the small per-row loads early; used only in the epilogue.
    float4 hv  = ((const float4*)hx)[row];
    float4 cxv = ((const float4*)cx)[row];

    float acc[16];
#pragma unroll
    for (int j = 0; j < 16; ++j) acc[j] = 0.0f;

    const float4* x4 = (const float4*)x;  // x is [NB][256] = [NB][64 float4]

    // Register prefetch pipeline: pre[] holds stage s+1 while LDS computes s.
    // f = tid + 128*u -> r = f>>3 in [0,128), c4 = f&7; 8 consecutive lanes
    // read one row's 128 B segment -> full-line coalescing.
    float4 pre[8];
#pragma unroll
    for (int u = 0; u < 8; ++u) {
        int f = tid + (u << 7);
        pre[u] = x4[(size_t)(row0 + (f >> 3)) * 64 + (f & 7)];
    }

    for (int stage = 0; stage < 8; ++stage) {
        // Commit prefetched stage into LDS (vmcnt wait lands here, after a
        // full compute phase of overlap).
#pragma unroll
        for (int u = 0; u < 8; ++u) {
            int f = tid + (u << 7);
            float* dst = &xs[(f >> 3) * 33 + ((f & 7) << 2)];
            dst[0] = pre[u].x; dst[1] = pre[u].y; dst[2] = pre[u].z; dst[3] = pre[u].w;
        }
        __syncthreads();

        // Issue next stage's global loads before computing this one.
        if (stage < 7) {
#pragma unroll
            for (int u = 0; u < 8; ++u) {
                int f = tid + (u << 7);
                pre[u] = x4[(size_t)(row0 + (f >> 3)) * 64 + (stage + 1) * 8 + (f & 7)];
            }
        }

        const float* xrow  = &xs[tid * 33];
        const float* wbase = Wp + stage * 32 * 16;
#pragma unroll
        for (int kk = 0; kk < 32; ++kk) {
            float xv = xrow[kk];
            const float* wp = wbase + kk * 16;  // wave-uniform -> s_load
#pragma unroll
            for (int j = 0; j < 16; ++j) acc[j] = fmaf(xv, wp[j], acc[j]);
        }
        __syncthreads();
    }

    // Tail: k = 256..259 come from hx[row][0..3].
    {
        const float* wp = Wp + 256 * 16;
#pragma unroll
        for (int j = 0; j < 16; ++j) acc[j] = fmaf(hv.x, wp[j],      acc[j]);
#pragma unroll
        for (int j = 0; j < 16; ++j) acc[j] = fmaf(hv.y, wp[16 + j], acc[j]);
#pragma unroll
        for (int j = 0; j < 16; ++j) acc[j] = fmaf(hv.z, wp[32 + j], acc[j]);
#pragma unroll
        for (int j = 0; j < 16; ++j) acc[j] = fmaf(hv.w, wp[48 + j], acc[j]);
    }

    // Quantum gate closed form: c_w = cos(angle_w + b_w + th_w);
    // E0 = c1*c2*c3, E1 = c0*c1, E2 = c0*c1*c2, E3 = c0*c1*c2*c3.
    float co[16];
#pragma unroll
    for (int j = 0; j < 16; ++j) co[j] = __cosf(acc[j] + bth[j]);

    float G[16];
#pragma unroll
    for (int g = 0; g < 4; ++g) {
        float c0 = co[g * 4 + 0], c1 = co[g * 4 + 1];
        float c2 = co[g * 4 + 2], c3 = co[g * 4 + 3];
        float e1 = c0 * c1;
        float e2 = e1 * c2;
        float e3 = e2 * c3;
        float e0 = c1 * c2 * c3;
        G[g * 4 + 0] = e0; G[g * 4 + 1] = e1; G[g * 4 + 2] = e2; G[g * 4 + 3] = e3;
    }

    float cxa[4] = {cxv.x, cxv.y, cxv.z, cxv.w};

    float hn[4], cn[4];
#pragma unroll
    for (int w = 0; w < 4; ++w) {
        float fg = sigm_(G[0 * 4 + w]);
        float ig = sigm_(G[1 * 4 + w]);
        float ug = tanh_(G[2 * 4 + w]);
        float og = sigm_(G[3 * 4 + w]);
        float c_ = fg * cxa[w] + ig * ug;
        cn[w] = c_;
        hn[w] = og * tanh_(c_);
    }

    ((float4*)out)[row]      = make_float4(hn[0], hn[1], hn[2], hn[3]);  // h_new
    ((float4*)out)[NB + row] = make_float4(cn[0], cn[1], cn[2], cn[3]);  // c_new
}

extern "C" void kernel_launch(void* const* d_in, const int* in_sizes, int n_in,
                              void* d_out, int out_size, void* d_ws, size_t ws_size,
                              hipStream_t stream) {
    const float* x   = (const float*)d_in[0];
    const float* hx  = (const float*)d_in[1];
    const float* cx  = (const float*)d_in[2];
    const float* Wf  = (const float*)d_in[3];
    const float* bf  = (const float*)d_in[4];
    const float* Wi  = (const float*)d_in[5];
    const float* bi  = (const float*)d_in[6];
    const float* Wu  = (const float*)d_in[7];
    const float* bu  = (const float*)d_in[8];
    const float* Wo  = (const float*)d_in[9];
    const float* bo  = (const float*)d_in[10];
    const float* thf = (const float*)d_in[11];
    const float* thi = (const float*)d_in[12];
    const float* thu = (const float*)d_in[13];
    const float* tho = (const float*)d_in[14];

    float* Wp  = (float*)d_ws;            // 260*16 floats = 16640 B
    float* bth = Wp + FANIN * 16;         // 16 floats

    qlstm_prep<<<(FANIN * 16 + 255) / 256, 256, 0, stream>>>(
        Wf, bf, Wi, bi, Wu, bu, Wo, bo, thf, thi, thu, tho, Wp, bth);

    qlstm_main<<<NB / TPB, TPB, 0, stream>>>(
        x, hx, cx, Wp, bth, (float*)d_out);
}

// Round 3
// 226.349 us; speedup vs baseline: 1.0107x; 1.0107x over previous
//
#include <hip/hip_runtime.h>

#define NB      131072   // batch rows
#define TPB     256      // 4 waves per block
#define RPB     64       // rows per block -> grid 2048 = 8 blocks/CU = 32 waves/CU
#define FANIN   260
#define XSTRIDE 34       // x-tile row stride in floats (136 B: 8B-aligned, uniform banks)
#define PSTRIDE 17       // partials row stride (odd -> 2-way banks, free)

__device__ __forceinline__ float sigm_(float x) { return 1.0f / (1.0f + __expf(-x)); }
__device__ __forceinline__ float tanh_(float x) { return 1.0f - 2.0f / (__expf(2.0f * x) + 1.0f); }

// Repack the four [4,260] weight matrices into k-major Wp[k][16] (col = g*4+w)
// and fuse bias+theta into bth[16]. Runs every launch (ws is re-poisoned).
__global__ void qlstm_prep(const float* __restrict__ Wf, const float* __restrict__ bf,
                           const float* __restrict__ Wi, const float* __restrict__ bi,
                           const float* __restrict__ Wu, const float* __restrict__ bu,
                           const float* __restrict__ Wo, const float* __restrict__ bo,
                           const float* __restrict__ thf, const float* __restrict__ thi,
                           const float* __restrict__ thu, const float* __restrict__ tho,
                           float* __restrict__ Wp, float* __restrict__ bth) {
    int t = blockIdx.x * blockDim.x + threadIdx.x;
    if (t < FANIN * 16) {
        int k = t >> 4, gw = t & 15, g = gw >> 2, w = gw & 3;
        const float* Wg = (g == 0) ? Wf : (g == 1) ? Wi : (g == 2) ? Wu : Wo;
        Wp[t] = Wg[w * FANIN + k];
    }
    if (t < 16) {
        int g = t >> 2, w = t & 3;
        const float* bg = (g == 0) ? bf  : (g == 1) ? bi  : (g == 2) ? bu  : bo;
        const float* tg = (g == 0) ? thf : (g == 1) ? thi : (g == 2) ? thu : tho;
        bth[t] = bg[w] + tg[w];
    }
}

__global__ __launch_bounds__(TPB, 8) void qlstm_main(
        const float* __restrict__ x, const float* __restrict__ hx,
        const float* __restrict__ cx, const float* __restrict__ Wp,
        const float* __restrict__ bth, float* __restrict__ out) {
    // smem serves two phases: [0..2176) = x tile (64 rows x 32 cols, stride 34);
    // after the last K-stage barrier it's reused as partials [3][64][17].
    __shared__ float smem[3 * RPB * PSTRIDE];   // 3264 floats = 13056 B

    const int tid  = threadIdx.x;
    const int row0 = blockIdx.x * RPB;
    const int r    = tid & 63;                                   // row within block
    const int w    = __builtin_amdgcn_readfirstlane(tid >> 6);   // wave id = k-slice

    const float4* x4 = (const float4*)x;

    // Role-specific small loads, issued early.
    float4 hv  = make_float4(0.f, 0.f, 0.f, 0.f);
    float4 cxv = make_float4(0.f, 0.f, 0.f, 0.f);
    if (w == 3) hv  = ((const float4*)hx)[row0 + r];   // tail k=256..259 owner
    if (w == 0) cxv = ((const float4*)cx)[row0 + r];   // epilogue owner

    // Staging role: 64 rows x 8 float4 per stage = 512 float4 / 256 thr = 2 each.
    const int r_st = tid >> 3;   // 0..31 (+32 for u=1)
    const int c4   = tid & 7;

    float4 pre[2];
#pragma unroll
    for (int u = 0; u < 2; ++u)
        pre[u] = x4[(size_t)(row0 + r_st + 32 * u) * 64 + c4];

    float acc[16];
#pragma unroll
    for (int j = 0; j < 16; ++j) acc[j] = 0.0f;

    const float* xrow = &smem[r * XSTRIDE + (w << 3)];  // my row, my wave's 8 cols

    for (int stage = 0; stage < 8; ++stage) {
        // Commit prefetched tile (float2 stores: 136r+16c4 is 8B-aligned).
#pragma unroll
        for (int u = 0; u < 2; ++u) {
            float* dst = &smem[(r_st + 32 * u) * XSTRIDE + (c4 << 2)];
            *(float2*)(dst)     = make_float2(pre[u].x, pre[u].y);
            *(float2*)(dst + 2) = make_float2(pre[u].z, pre[u].w);
        }
        __syncthreads();

        if (stage < 7) {
#pragma unroll
            for (int u = 0; u < 2; ++u)
                pre[u] = x4[(size_t)(row0 + r_st + 32 * u) * 64 + ((stage + 1) << 3) + c4];
        }

        // Wave w consumes cols [8w, 8w+8) of this 32-col stage.
        // Weight address is wave-uniform -> scalar s_load path.
        const float* wbase = Wp + (((stage << 5) + (w << 3)) << 4);
#pragma unroll
        for (int k2 = 0; k2 < 4; ++k2) {
            float2 xv = *(const float2*)(xrow + (k2 << 1));
            const float* wp0 = wbase + (k2 << 5);
#pragma unroll
            for (int j = 0; j < 16; ++j) acc[j] = fmaf(xv.x, wp0[j],      acc[j]);
#pragma unroll
            for (int j = 0; j < 16; ++j) acc[j] = fmaf(xv.y, wp0[16 + j], acc[j]);
        }
        __syncthreads();
    }

    // Tail k = 256..259 (hx), owned by wave 3.
    if (w == 3) {
        const float* wp = Wp + 256 * 16;
#pragma unroll
        for (int j = 0; j < 16; ++j) acc[j] = fmaf(hv.x, wp[j],      acc[j]);
#pragma unroll
        for (int j = 0; j < 16; ++j) acc[j] = fmaf(hv.y, wp[16 + j], acc[j]);
#pragma unroll
        for (int j = 0; j < 16; ++j) acc[j] = fmaf(hv.z, wp[32 + j], acc[j]);
#pragma unroll
        for (int j = 0; j < 16; ++j) acc[j] = fmaf(hv.w, wp[48 + j], acc[j]);
    }

    // Waves 1..3 publish partials into smem (x tile is dead past the last sync).
    if (w > 0) {
        float* p = &smem[(w - 1) * (RPB * PSTRIDE) + r * PSTRIDE];
#pragma unroll
        for (int j = 0; j < 16; ++j) p[j] = acc[j];
    }
    __syncthreads();

    if (w == 0) {
        // Reduce the 4 k-slices for my row.
#pragma unroll
        for (int wm = 0; wm < 3; ++wm) {
            const float* p = &smem[wm * (RPB * PSTRIDE) + r * PSTRIDE];
#pragma unroll
            for (int j = 0; j < 16; ++j) acc[j] += p[j];
        }

        // Quantum gate closed form: c_w = cos(angle + bias + theta);
        // E0 = c1c2c3, E1 = c0c1, E2 = c0c1c2, E3 = c0c1c2c3 (per gate).
        float co[16];
#pragma unroll
        for (int j = 0; j < 16; ++j) co[j] = __cosf(acc[j] + bth[j]);

        float G[16];
#pragma unroll
        for (int g = 0; g < 4; ++g) {
            float c0 = co[g * 4 + 0], c1 = co[g * 4 + 1];
            float c2 = co[g * 4 + 2], c3 = co[g * 4 + 3];
            float e1 = c0 * c1;
            float e2 = e1 * c2;
            float e3 = e2 * c3;
            float e0 = c1 * c2 * c3;
            G[g * 4 + 0] = e0; G[g * 4 + 1] = e1; G[g * 4 + 2] = e2; G[g * 4 + 3] = e3;
        }

        float cxa[4] = {cxv.x, cxv.y, cxv.z, cxv.w};
        float hn[4], cn[4];
#pragma unroll
        for (int wi = 0; wi < 4; ++wi) {
            float fg = sigm_(G[0 * 4 + wi]);
            float ig = sigm_(G[1 * 4 + wi]);
            float ug = tanh_(G[2 * 4 + wi]);
            float og = sigm_(G[3 * 4 + wi]);
            float c_ = fg * cxa[wi] + ig * ug;
            cn[wi] = c_;
            hn[wi] = og * tanh_(c_);
        }

        ((float4*)out)[row0 + r]      = make_float4(hn[0], hn[1], hn[2], hn[3]);
        ((float4*)out)[NB + row0 + r] = make_float4(cn[0], cn[1], cn[2], cn[3]);
    }
}

extern "C" void kernel_launch(void* const* d_in, const int* in_sizes, int n_in,
                              void* d_out, int out_size, void* d_ws, size_t ws_size,
                              hipStream_t stream) {
    const float* x   = (const float*)d_in[0];
    const float* hx  = (const float*)d_in[1];
    const float* cx  = (const float*)d_in[2];
    const float* Wf  = (const float*)d_in[3];
    const float* bf  = (const float*)d_in[4];
    const float* Wi  = (const float*)d_in[5];
    const float* bi  = (const float*)d_in[6];
    const float* Wu  = (const float*)d_in[7];
    const float* bu  = (const float*)d_in[8];
    const float* Wo  = (const float*)d_in[9];
    const float* bo  = (const float*)d_in[10];
    const float* thf = (const float*)d_in[11];
    const float* thi = (const float*)d_in[12];
    const float* thu = (const float*)d_in[13];
    const float* tho = (const float*)d_in[14];

    float* Wp  = (float*)d_ws;            // 260*16 floats = 16640 B
    float* bth = Wp + FANIN * 16;         // 16 floats

    qlstm_prep<<<(FANIN * 16 + 255) / 256, 256, 0, stream>>>(
        Wf, bf, Wi, bi, Wu, bu, Wo, bo, thf, thi, thu, tho, Wp, bth);

    qlstm_main<<<NB / RPB, TPB, 0, stream>>>(
        x, hx, cx, Wp, bth, (float*)d_out);
}